// Round 8
// baseline (47.969 us; speedup 1.0000x reference)
//
#include <hip/hip_runtime.h>

#define N_RBF 16
#define N_HIDDEN 32
#define BLOCK 256                 // 4 waves: wave = (atom in {0,1}) x (half-range in {0,1})
#define QCAP 512                  // per-wave queue; mu=318, +8sigma ~ 420 < 512

// Gaussian-grid recurrence (a = 4.5, w = 1/3):
//   r_k = exp(-a (d - k w)^2); r_0 = exp(-a d^2); r_{k+1} = r_k * s_k,
//   s_k = exp(3d - 0.5 - k).  Even/odd split for ILP.
// Chain scaled by 2^80 so r_0 never underflows for d < 5.
#define LOG2E 1.44269504088896340736f
#define NC   (-4.5f * LOG2E)
#define S0A  (3.0f * LOG2E)
#define S0B  (-0.5f * LOG2E)
#define BIAS 80.0f
#define UNSC 8.271806125530277e-25f     // 2^-80
#define C_E1 0.36787944117144233f       // e^-1
#define C_E3 0.049787068367863944f      // e^-3
#define C_E4 0.018315638888734179f      // e^-4

__device__ __forceinline__ float rfl(float x) {
    return __int_as_float(__builtin_amdgcn_readfirstlane(__float_as_int(x)));
}

__device__ __forceinline__ void rbf_batch(float d2, bool active, float (&feat)[N_RBF]) {
    d2 = active ? d2 : 1.0f;          // masked lanes: benign arg, no inf/NaN
    float d  = __builtin_amdgcn_sqrtf(d2);
    float r0 = __builtin_amdgcn_exp2f(fmaf(d2, NC, BIAS));   // 2^80 * exp(-a d^2)
    float s  = __builtin_amdgcn_exp2f(fmaf(d, S0A, S0B));    // exp(3d - 0.5)
    float r1 = r0 * s;
    if (!active) { r0 = 0.0f; r1 = 0.0f; }
    float s2 = s * s;
    float ue = s2 * C_E1;
    float uo = s2 * C_E3;
    #pragma unroll
    for (int k = 0; k < N_RBF; k += 2) {
        feat[k]     += r0;
        feat[k + 1] += r1;
        r0 *= ue;  r1 *= uo;
        ue *= C_E4; uo *= C_E4;
    }
}

// Transpose-reduce 16 per-lane partials across 64 lanes.
// Lanes with (lane&3)==0 return the wave-sum of feature k=(lane>>2).
__device__ __forceinline__ float treduce(float (&f)[N_RBF], int lane) {
    float w1r[8];
    #pragma unroll
    for (int k = 0; k < 8; ++k) {
        float lo = f[k], hi = f[k + 8];
        float lo2 = __shfl_xor(lo, 32, 64);
        float hi2 = __shfl_xor(hi, 32, 64);
        w1r[k] = (lane & 32) ? (hi + hi2) : (lo + lo2);
    }
    float w2r[4];
    #pragma unroll
    for (int k = 0; k < 4; ++k) {
        float lo = w1r[k], hi = w1r[k + 4];
        float lo2 = __shfl_xor(lo, 16, 64);
        float hi2 = __shfl_xor(hi, 16, 64);
        w2r[k] = (lane & 16) ? (hi + hi2) : (lo + lo2);
    }
    float w3r[2];
    #pragma unroll
    for (int k = 0; k < 2; ++k) {
        float lo = w2r[k], hi = w2r[k + 2];
        float lo2 = __shfl_xor(lo, 8, 64);
        float hi2 = __shfl_xor(hi, 8, 64);
        w3r[k] = (lane & 8) ? (hi + hi2) : (lo + lo2);
    }
    float lo2 = __shfl_xor(w3r[0], 4, 64);
    float hi2 = __shfl_xor(w3r[1], 4, 64);
    float w4 = (lane & 4) ? (w3r[1] + hi2) : (w3r[0] + lo2);
    w4 += __shfl_xor(w4, 2, 64);
    w4 += __shfl_xor(w4, 1, 64);
    return w4;
}

__global__ __launch_bounds__(256)
void pack_kernel(const float* __restrict__ pos, float4* __restrict__ ppos,
                 float* __restrict__ out, int n, int npad)
{
    int i = blockIdx.x * 256 + threadIdx.x;
    if (i == 0) out[0] = 0.0f;
    if (i < npad) {
        float4 v;
        if (i < n) { v.x = pos[3*i]; v.y = pos[3*i+1]; v.z = pos[3*i+2]; v.w = 0.f; }
        else       { v.x = 1e9f;     v.y = 1e9f;       v.z = 1e9f;       v.w = 0.f; }
        ppos[i] = v;
    }
}

__global__ __launch_bounds__(BLOCK, 8)    // 8 waves/SIMD -> <=64 VGPR, 8 blocks/CU
void ag3sr_main(const float4* __restrict__ ppos,   // [npad] sentinel-padded
                const float* __restrict__ W1,      // [16,32]
                const float* __restrict__ b1,      // [32]
                const float* __restrict__ W2,      // [32]
                const float* __restrict__ b2,      // [1]
                float* __restrict__ out,           // [1]
                int n, int halfr)                  // halfr = npad/2 (mult of 64)
{
    __shared__ float sq[4][QCAP];          // 8 KB: one queue per wave
    __shared__ float sfeat[4][N_RBF];      // per-wave reduced features
    __shared__ float sW1[N_RBF * N_HIDDEN];
    __shared__ float sb1[N_HIDDEN], sW2[N_HIDDEN];

    const int tid  = threadIdx.x;
    const int wave = tid >> 6;
    const int lane = tid & 63;
    const int a0   = blockIdx.x * 2;           // block owns atoms a0, a0+1
    const int atom = a0 + (wave >> 1);         // this wave's atom
    const int halfid = wave & 1;               // this wave's j half-range

    for (int idx = tid; idx < N_RBF * N_HIDDEN; idx += BLOCK) sW1[idx] = W1[idx];
    if (tid < N_HIDDEN) { sb1[tid] = b1[tid]; sW2[tid] = W2[tid]; }

    float4 pa = ppos[atom];
    const float xa = rfl(pa.x), ya = rfl(pa.y), za = rfl(pa.z);

    float feat[N_RBF];
    #pragma unroll
    for (int k = 0; k < N_RBF; ++k) feat[k] = 0.0f;

    // ---- Phase A: compaction with 1-deep software-pipelined prefetch ----
    const int jb = halfid * halfr;
    const int iters = halfr >> 6;              // 32 for n=4096
    int c = 0;

#define PROC(PJ)                                                              \
    {                                                                         \
        float dx = (PJ).x - xa, dy = (PJ).y - ya, dz = (PJ).z - za;           \
        float q = fmaf(dz, dz, fmaf(dy, dy, dx * dx));                        \
        bool p = (q > 0.0f) & (q < 25.0f);                                    \
        unsigned long long m = __ballot(p);                                   \
        int pr = __builtin_amdgcn_mbcnt_hi((unsigned)(m >> 32),               \
                  __builtin_amdgcn_mbcnt_lo((unsigned)m, 0u));                \
        int sl = c + pr;                                                      \
        if (p && sl < QCAP) sq[wave][sl] = q;                                 \
        c += __popcll(m);                                                     \
        if (c > QCAP) rbf_batch(q, p && sl >= QCAP, feat);  /* ~never */      \
    }

    float4 buf = ppos[jb + lane];
    for (int it = 0; it < iters - 1; ++it) {
        float4 nxt = ppos[jb + ((it + 1) << 6) + lane];   // prefetch next
        PROC(buf);
        buf = nxt;
    }
    PROC(buf);
#undef PROC

    // ---- Phase B: dense wave-private drain (stride-1 ds_reads) ----
    {
        const int cc = c < QCAP ? c : QCAP;
        for (int b = 0; b < cc; b += 64) {
            int idx = b + lane;
            bool act = idx < cc;
            float qd2 = sq[wave][act ? idx : 0];
            rbf_batch(qd2, act, feat);
        }
    }

    // ---- Epilogue: wave-reduce, block-combine, MLP, one atomic ----
    float w4 = treduce(feat, lane);
    if ((lane & 3) == 0) sfeat[wave][lane >> 2] = w4;
    __syncthreads();

    if (tid < 64) {                            // wave 0: both atoms' MLP
        const int a = tid >> 5, h = tid & 31;
        const bool valid = (a0 + a) < n;
        float e = 0.0f;
        if (valid) {
            float acc = sb1[h];
            #pragma unroll
            for (int k = 0; k < N_RBF; ++k) {
                float f = (sfeat[a * 2][k] + sfeat[a * 2 + 1][k]) * UNSC;
                acc = fmaf(f, sW1[k * N_HIDDEN + h], acc);
            }
            float sg = 1.0f / (1.0f + __builtin_amdgcn_exp2f(-acc * LOG2E));
            e = acc * sg * sW2[h];
            if (h == 0) e += b2[0];
        }
        #pragma unroll
        for (int off = 16; off > 0; off >>= 1) e += __shfl_xor(e, off, 64);
        e += __shfl_xor(e, 32, 64);            // combine the two atoms
        if (tid == 0) atomicAdd(out, e);
    }
}

extern "C" void kernel_launch(void* const* d_in, const int* in_sizes, int n_in,
                              void* d_out, int out_size, void* d_ws, size_t ws_size,
                              hipStream_t stream) {
    const float* pos = (const float*)d_in[0];
    const float* W1  = (const float*)d_in[1];
    const float* b1  = (const float*)d_in[2];
    const float* W2  = (const float*)d_in[3];
    const float* b2  = (const float*)d_in[4];
    float* out = (float*)d_out;

    const int n     = in_sizes[0] / 3;
    const int npad  = (n + 127) & ~127;     // two halves, each mult of 64
    const int halfr = npad >> 1;

    float4* ppos = (float4*)d_ws;           // 16*npad bytes of scratch

    pack_kernel<<<(npad + 255) / 256, 256, 0, stream>>>(pos, ppos, out, n, npad);

    const int grid = npad / 2;              // 2 atoms per block
    ag3sr_main<<<grid, BLOCK, 0, stream>>>(ppos, W1, b1, W2, b2, out, n, halfr);
}